// Round 13
// baseline (363.593 us; speedup 1.0000x reference)
//
#include <hip/hip_runtime.h>
#include <hip/hip_bf16.h>
#include <math.h>

#define T_TOK 8192
#define D_DIM 2048
#define O_DIM 2048
#define E_NUM 8
#define XCAP 4096          // per-expert row capacity in permuted buffer
#define BM 256
#define BN 256
#define BK 64

typedef __bf16 bf16_t;
typedef __bf16 bf16x8 __attribute__((ext_vector_type(8)));
typedef float fx4 __attribute__((ext_vector_type(4)));
typedef unsigned short us4 __attribute__((ext_vector_type(4)));

__device__ __forceinline__ unsigned short f2bf(float f) {
    unsigned int u = __builtin_bit_cast(unsigned int, f);
    u += 0x7FFFu + ((u >> 16) & 1u);           // round-to-nearest-even
    return (unsigned short)(u >> 16);
}

__device__ __forceinline__ void gll16(const void* g, void* l) {
    __builtin_amdgcn_global_load_lds(
        (const __attribute__((address_space(1))) void*)g,
        (__attribute__((address_space(3))) void*)l, 16, 0, 0);
}

// ---------------------------------------------------------------- convert W
__global__ __launch_bounds__(256) void convert_w_kernel(
    const float* __restrict__ w, bf16_t* __restrict__ wb) {
    long base = (long)blockIdx.x * 2048 + threadIdx.x;
    const float4* w4 = (const float4*)w;
    us4* o4 = (us4*)wb;
    float4 v[8];
#pragma unroll
    for (int k = 0; k < 8; ++k) v[k] = w4[base + k * 256];
#pragma unroll
    for (int k = 0; k < 8; ++k) {
        us4 o = { f2bf(v[k].x), f2bf(v[k].y), f2bf(v[k].z), f2bf(v[k].w) };
        o4[base + k * 256] = o;
    }
}

// ---------------------------------------------------------------- gating
// one wave per token: fp32 logits, top-2, softmax, push to lists, AND
// fused permute: the wave writes its converted bf16 row directly into
// xg[e][slot] for BOTH selected experts (contiguous 4KB row writes).
// This moves the token gather OUT of the GEMM's global_load_lds path.
__global__ __launch_bounds__(256) void gate_kernel(
    const float* __restrict__ x, const float* __restrict__ gw,
    bf16_t* __restrict__ xg, int* __restrict__ cnt,
    int* __restrict__ tok_list, float* __restrict__ wgt_list) {
    int wid = threadIdx.x >> 6, lane = threadIdx.x & 63;
    int t = blockIdx.x * 4 + wid;

    const float4* xrow = (const float4*)(x + (size_t)t * D_DIM);
    float4 xv[8];
#pragma unroll
    for (int i = 0; i < 8; ++i) xv[i] = xrow[i * 64 + lane];

    float acc[E_NUM];
#pragma unroll
    for (int e = 0; e < E_NUM; ++e) {
        const float4* gr = (const float4*)(gw + (size_t)e * D_DIM);
        float s = 0.f;
#pragma unroll
        for (int i = 0; i < 8; ++i) {
            float4 g = gr[i * 64 + lane];
            s += xv[i].x * g.x + xv[i].y * g.y + xv[i].z * g.z + xv[i].w * g.w;
        }
        acc[e] = s;
    }
#pragma unroll
    for (int m = 1; m < 64; m <<= 1) {
#pragma unroll
        for (int e = 0; e < E_NUM; ++e) acc[e] += __shfl_xor(acc[e], m, 64);
    }

    us4 o[8];
#pragma unroll
    for (int i = 0; i < 8; ++i) {
        us4 ov = { f2bf(xv[i].x), f2bf(xv[i].y), f2bf(xv[i].z), f2bf(xv[i].w) };
        o[i] = ov;
    }

    int loc0 = 0, loc1 = 0;
    if (lane == 0) {
        int e0 = 0; float v0 = acc[0];
#pragma unroll
        for (int e = 1; e < E_NUM; ++e)
            if (acc[e] > v0) { v0 = acc[e]; e0 = e; }
        int e1 = -1; float v1 = -INFINITY;
#pragma unroll
        for (int e = 0; e < E_NUM; ++e)
            if (e != e0 && acc[e] > v1) { v1 = acc[e]; e1 = e; }
        float p1 = expf(v1 - v0);
        float denom = 1.f + p1;
        float w0 = 1.f / denom, w1 = p1 / denom;
        int s0 = atomicAdd(&cnt[e0 * 16], 1);
        tok_list[e0 * T_TOK + s0] = (t << 1);      // slot 0 -> out
        wgt_list[e0 * T_TOK + s0] = w0;
        int s1 = atomicAdd(&cnt[e1 * 16], 1);
        tok_list[e1 * T_TOK + s1] = (t << 1) | 1;  // slot 1 -> part
        wgt_list[e1 * T_TOK + s1] = w1;
        loc0 = e0 * XCAP + s0;
        loc1 = e1 * XCAP + s1;
    }
    loc0 = __shfl(loc0, 0, 64);
    loc1 = __shfl(loc1, 0, 64);

    us4* d0 = (us4*)(xg + (size_t)loc0 * D_DIM);
    us4* d1 = (us4*)(xg + (size_t)loc1 * D_DIM);
#pragma unroll
    for (int i = 0; i < 8; ++i) d0[i * 64 + lane] = o[i];
#pragma unroll
    for (int i = 0; i < 8; ++i) d1[i * 64 + lane] = o[i];
}

// ---------------------------------------------------------------- expert GEMM
// Byte-identical to round 12 (best: 229us, conflicts=0, XCD-mapped) EXCEPT
// the A source: reads the PERMUTED activation buffer xg[e*XCAP + row] —
// contiguous rows, same addressing pattern as B. This isolates the last
// structural delta vs the dense m201 reference: scattered-gather A staging
// (16 random 64B sectors per gll16, completion-tail exposed at every vmcnt)
// vs contiguous panels. Scatter remains only in the epilogue STORES
// (fire-and-forget, never implicated).
__global__ __launch_bounds__(512, 1) void expert_gemm(
    const bf16_t* __restrict__ xg, const bf16_t* __restrict__ wb,
    const float* __restrict__ eb, const int* __restrict__ cnt,
    const int* __restrict__ tok_list, const float* __restrict__ wgt_list,
    float* __restrict__ out, float* __restrict__ part) {
    int bid = blockIdx.x;
    int e = bid & 7;                          // XCD-resident expert
    int slot = bid >> 3;                      // 0..255 within expert
    int count = cnt[e * 16];
    int mt = (count + BM - 1) / BM;           // active m-tiles this expert
    if (slot >= mt * 8) return;
    int m0 = (slot >> 3) * BM;
    int n0 = (slot & 7) * BN;

    __shared__ alignas(16) unsigned char LDSB[131072];
    __shared__ int tok_s[BM];
    __shared__ float wgt_s[BM];

    int tid = threadIdx.x, wid = tid >> 6, L = tid & 63;
    int wr = wid >> 2, wc = wid & 3;          // 2 x 4 wave grid

    if (tid < BM) {
        int idx = m0 + tid;
        if (idx >= count) idx = count - 1;    // clamp; masked in epilogue
        tok_s[tid] = tok_list[e * T_TOK + idx];
        wgt_s[tid] = wgt_list[e * T_TOK + idx];
    }
    __syncthreads();

    // ---- staging geometry (r10 swizzle, conflict-free) ----
    int rA0 = wid * 16 + (L >> 2);            // call-0 row (0..127)
    int rA1 = rA0 + 128;                      // call-1 row
    int kcol = ((L & 3) ^ ((L >> 3) & 3)) * 8;  // pre-swizzled k-chunk (elems)
    int ar0 = m0 + rA0; if (ar0 >= count) ar0 = count - 1;   // contiguous rows
    int ar1 = m0 + rA1; if (ar1 >= count) ar1 = count - 1;
    const bf16_t* gA0 = xg + (size_t)(e * XCAP + ar0) * D_DIM + kcol;
    const bf16_t* gA1 = xg + (size_t)(e * XCAP + ar1) * D_DIM + kcol;
    const bf16_t* wbase = wb + (size_t)e * O_DIM * D_DIM;
    const bf16_t* gB0 = wbase + (size_t)(n0 + rA0) * D_DIM + kcol;
    const bf16_t* gB1 = wbase + (size_t)(n0 + rA1) * D_DIM + kcol;
    unsigned sW = wid * 1024;                 // wave-uniform LDS offset, call0

#define STAGE_A(db, hh, koff) do {                                          \
        unsigned bb = (db) * 65536u + (hh) * 16384u + sW;                   \
        gll16(gA0 + (koff), LDSB + bb);                                     \
        gll16(gA1 + (koff), LDSB + bb + 8192); } while (0)
#define STAGE_B(db, hh, koff) do {                                          \
        unsigned bb = (db) * 65536u + 32768u + (hh) * 16384u + sW;          \
        gll16(gB0 + (koff), LDSB + bb);                                     \
        gll16(gB1 + (koff), LDSB + bb + 8192); } while (0)

    // ---- read geometry (r10): slot = (L>>4) ^ ((L>>1)&3) ----
    unsigned xorp = ((unsigned)((L >> 4) ^ ((L >> 1) & 3))) * 16u;
    unsigned rowA = (unsigned)(wr * 128 + (L & 15)) * 64u;
    unsigned rowB = (unsigned)(wc * 64 + (L & 15)) * 64u;

#define LDA(base, MB)                                                       \
    _Pragma("unroll") for (int mm = 0; mm < 4; ++mm)                        \
        aq[mm] = *(const bf16x8*)(LDSB + (base) + rowA + (MB + mm) * 1024u + xorp);
#define LDB(base)                                                           \
    _Pragma("unroll") for (int nn = 0; nn < 4; ++nn)                        \
        bq[nn] = *(const bf16x8*)(LDSB + (base) + 32768u + rowB + nn * 1024u + xorp);
#define PH_MFMA(MB)                                                         \
    __builtin_amdgcn_s_setprio(1);                                          \
    _Pragma("unroll") for (int mm = 0; mm < 4; ++mm)                        \
        _Pragma("unroll") for (int nn = 0; nn < 4; ++nn)                    \
            acc[MB + mm][nn] = __builtin_amdgcn_mfma_f32_16x16x32_bf16(     \
                aq[mm], bq[nn], acc[MB + mm][nn], 0, 0, 0);                  \
    __builtin_amdgcn_s_setprio(0);
#define PHEND_LG  { asm volatile("s_waitcnt lgkmcnt(0)" ::: "memory");      \
                    __builtin_amdgcn_s_barrier();                           \
                    asm volatile("" ::: "memory"); }
#define PHEND_V8  { asm volatile("s_waitcnt vmcnt(8) lgkmcnt(0)" ::: "memory"); \
                    __builtin_amdgcn_s_barrier();                           \
                    asm volatile("" ::: "memory"); }
#define PHEND_V0  { asm volatile("s_waitcnt vmcnt(0) lgkmcnt(0)" ::: "memory"); \
                    __builtin_amdgcn_s_barrier();                           \
                    asm volatile("" ::: "memory"); }

    fx4 acc[8][4];
#pragma unroll
    for (int m = 0; m < 8; ++m)
#pragma unroll
        for (int n = 0; n < 4; ++n) acc[m][n] = (fx4)0.f;

    const int NT = D_DIM / BK;                // 32
    // prologue: tile0 all 4 halves -> dbuf0, tile1 kh0 -> dbuf1.
    STAGE_A(0, 0, 0);   STAGE_B(0, 0, 0);
    STAGE_A(0, 1, 32);  STAGE_B(0, 1, 32);
    STAGE_A(1, 0, 64);  STAGE_B(1, 0, 64);
    PHEND_V8;

    for (int t = 0; t < NT; ++t) {
        const int d = t & 1;
        const unsigned CA = (unsigned)d * 65536u;
        bf16x8 aq[4], bq[4];
        // ---- ph1: kh0, m0-3 (+B kh0) ----
        LDA(CA, 0); LDB(CA);
        if (t + 1 < NT) STAGE_A(d ^ 1, 1, (t + 1) * 64 + 32);
        PHEND_LG;
        PH_MFMA(0);
        // ---- ph2: kh0, m4-7 (B reused in regs) ----
        LDA(CA, 4);
        if (t + 1 < NT) { STAGE_B(d ^ 1, 1, (t + 1) * 64 + 32); PHEND_V8; }
        else            { PHEND_V0; }
        PH_MFMA(4);
        // ---- ph3: kh1, m0-3 (+B kh1) ----
        LDA(CA + 16384u, 0); LDB(CA + 16384u);
        if (t + 2 < NT) STAGE_A(d, 0, (t + 2) * 64);
        PHEND_LG;
        PH_MFMA(0);
        // ---- ph4: kh1, m4-7 ----
        LDA(CA + 16384u, 4);
        if (t + 2 < NT) { STAGE_B(d, 0, (t + 2) * 64); PHEND_V8; }
        else            { PHEND_V0; }
        PH_MFMA(4);
    }
#undef STAGE_A
#undef STAGE_B
#undef LDA
#undef LDB
#undef PH_MFMA
#undef PHEND_LG
#undef PHEND_V8
#undef PHEND_V0

    // epilogue: C/D layout col=L&15, row=(L>>4)*4+j. Plain scatter stores.
    const float* ebias = eb + (size_t)e * O_DIM;
    int rr = L & 15, kq = L >> 4;
#pragma unroll
    for (int n = 0; n < 4; ++n) {
        int gcol = n0 + wc * 64 + n * 16 + rr;
        float bias = ebias[gcol];
#pragma unroll
        for (int m = 0; m < 8; ++m) {
            int rbase = wr * 128 + m * 16 + kq * 4;
#pragma unroll
            for (int j = 0; j < 4; ++j) {
                int r = rbase + j;
                if (m0 + r < count) {
                    int entry = tok_s[r];
                    float v = wgt_s[r] * (acc[m][n][j] + bias);
                    float* dst = (entry & 1) ? part : out;
                    dst[(size_t)(entry >> 1) * O_DIM + gcol] = v;
                }
            }
        }
    }
}

// ---------------------------------------------------------------- combine
__global__ __launch_bounds__(256) void combine_kernel(
    float* __restrict__ out, const float* __restrict__ part, long n4) {
    long i = (long)blockIdx.x * blockDim.x + threadIdx.x;
    long stride = (long)gridDim.x * blockDim.x;
    float4* o4 = (float4*)out;
    const float4* p4 = (const float4*)part;
    for (; i < n4; i += stride) {
        float4 a = o4[i], b = p4[i];
        a.x += b.x; a.y += b.y; a.z += b.z; a.w += b.w;
        o4[i] = a;
    }
}

// ---------------------------------------------------------------- launch
extern "C" void kernel_launch(void* const* d_in, const int* in_sizes, int n_in,
                              void* d_out, int out_size, void* d_ws, size_t ws_size,
                              hipStream_t stream) {
    const float* x        = (const float*)d_in[0];
    const float* gate_w   = (const float*)d_in[1];
    const float* expert_w = (const float*)d_in[2];
    const float* expert_b = (const float*)d_in[3];
    float* out = (float*)d_out;

    char* ws = (char*)d_ws;
    size_t off = 0;
    bf16_t* wb = (bf16_t*)(ws + off);      off += (size_t)E_NUM * O_DIM * D_DIM * 2;
    bf16_t* xg = (bf16_t*)(ws + off);      off += (size_t)E_NUM * XCAP * D_DIM * 2;
    float*  part = (float*)(ws + off);     off += (size_t)T_TOK * O_DIM * 4;
    int*    tok_list = (int*)(ws + off);   off += (size_t)E_NUM * T_TOK * 4;
    float*  wgt_list = (float*)(ws + off); off += (size_t)E_NUM * T_TOK * 4;
    int*    cnt = (int*)(ws + off);        off += 512;   // 8 counters, 64B apart

    hipMemsetAsync(cnt, 0, 512, stream);

    convert_w_kernel<<<4096, 256, 0, stream>>>(expert_w, wb);
    gate_kernel<<<T_TOK / 4, 256, 0, stream>>>(
        x, gate_w, xg, cnt, tok_list, wgt_list);
    expert_gemm<<<2048, 512, 0, stream>>>(
        xg, wb, expert_b, cnt, tok_list, wgt_list, out, part);
    combine_kernel<<<2048, 256, 0, stream>>>(
        out, part, (long)T_TOK * O_DIM / 4);
}

// Round 14
// 325.286 us; speedup vs baseline: 1.1178x; 1.1178x over previous
//
#include <hip/hip_runtime.h>
#include <hip/hip_bf16.h>
#include <math.h>

#define T_TOK 8192
#define D_DIM 2048
#define O_DIM 2048
#define E_NUM 8
#define BM 256
#define BN 256
#define BK 64

typedef __bf16 bf16_t;
typedef __bf16 bf16x8 __attribute__((ext_vector_type(8)));
typedef float fx4 __attribute__((ext_vector_type(4)));
typedef unsigned short us4 __attribute__((ext_vector_type(4)));

__device__ __forceinline__ unsigned short f2bf(float f) {
    unsigned int u = __builtin_bit_cast(unsigned int, f);
    u += 0x7FFFu + ((u >> 16) & 1u);           // round-to-nearest-even
    return (unsigned short)(u >> 16);
}

__device__ __forceinline__ void gll16(const void* g, void* l) {
    __builtin_amdgcn_global_load_lds(
        (const __attribute__((address_space(1))) void*)g,
        (__attribute__((address_space(3))) void*)l, 16, 0, 0);
}

// ---------------------------------------------------------------- convert W
// Also zeroes the cnt counters (fold of the former hipMemsetAsync dispatch).
// convert_w completes before gate starts (stream order) -> race-free.
__global__ __launch_bounds__(256) void convert_w_kernel(
    const float* __restrict__ w, bf16_t* __restrict__ wb, int* __restrict__ cnt) {
    if (blockIdx.x == 0 && threadIdx.x < 128) cnt[threadIdx.x] = 0;
    long base = (long)blockIdx.x * 2048 + threadIdx.x;
    const float4* w4 = (const float4*)w;
    us4* o4 = (us4*)wb;
    float4 v[8];
#pragma unroll
    for (int k = 0; k < 8; ++k) v[k] = w4[base + k * 256];
#pragma unroll
    for (int k = 0; k < 8; ++k) {
        us4 o = { f2bf(v[k].x), f2bf(v[k].y), f2bf(v[k].z), f2bf(v[k].w) };
        o4[base + k * 256] = o;
    }
}

// ---------------------------------------------------------------- gating
// one wave per token; padded counters (cnt[e*16], 64B apart).
__global__ __launch_bounds__(256) void gate_kernel(
    const float* __restrict__ x, const float* __restrict__ gw,
    bf16_t* __restrict__ xb, int* __restrict__ cnt,
    int* __restrict__ tok_list, float* __restrict__ wgt_list) {
    int wid = threadIdx.x >> 6, lane = threadIdx.x & 63;
    int t = blockIdx.x * 4 + wid;

    const float4* xrow = (const float4*)(x + (size_t)t * D_DIM);
    float4 xv[8];
#pragma unroll
    for (int i = 0; i < 8; ++i) xv[i] = xrow[i * 64 + lane];

    float acc[E_NUM];
#pragma unroll
    for (int e = 0; e < E_NUM; ++e) {
        const float4* gr = (const float4*)(gw + (size_t)e * D_DIM);
        float s = 0.f;
#pragma unroll
        for (int i = 0; i < 8; ++i) {
            float4 g = gr[i * 64 + lane];
            s += xv[i].x * g.x + xv[i].y * g.y + xv[i].z * g.z + xv[i].w * g.w;
        }
        acc[e] = s;
    }
#pragma unroll
    for (int m = 1; m < 64; m <<= 1) {
#pragma unroll
        for (int e = 0; e < E_NUM; ++e) acc[e] += __shfl_xor(acc[e], m, 64);
    }

    us4* xbr = (us4*)(xb + (size_t)t * D_DIM);
#pragma unroll
    for (int i = 0; i < 8; ++i) {
        us4 o = { f2bf(xv[i].x), f2bf(xv[i].y), f2bf(xv[i].z), f2bf(xv[i].w) };
        xbr[i * 64 + lane] = o;
    }

    if (lane == 0) {
        int e0 = 0; float v0 = acc[0];
#pragma unroll
        for (int e = 1; e < E_NUM; ++e)
            if (acc[e] > v0) { v0 = acc[e]; e0 = e; }
        int e1 = -1; float v1 = -INFINITY;
#pragma unroll
        for (int e = 0; e < E_NUM; ++e)
            if (e != e0 && acc[e] > v1) { v1 = acc[e]; e1 = e; }
        float p1 = expf(v1 - v0);
        float denom = 1.f + p1;
        float w0 = 1.f / denom, w1 = p1 / denom;
        int s0 = atomicAdd(&cnt[e0 * 16], 1);
        tok_list[e0 * T_TOK + s0] = (t << 1);      // slot 0 -> out
        wgt_list[e0 * T_TOK + s0] = w0;
        int s1 = atomicAdd(&cnt[e1 * 16], 1);
        tok_list[e1 * T_TOK + s1] = (t << 1) | 1;  // slot 1 -> part
        wgt_list[e1 * T_TOK + s1] = w1;
    }
}

// ---------------------------------------------------------------- expert GEMM
// Byte-identical to round 12 (best measured: 229 us, conflicts = 0,
// XCD-mapped, FETCH 111 MB). r13's permuted-A variant was a null/regression
// and is reverted. Structure: 256x256 tile, BK=64, 8 waves (2Mx4N), 4-phase
// K-half double-buffer, counted vmcnt(8), conflict-free (r>>1)&3 XOR swizzle
// applied on both staging source and ds_read address, expert-per-XCD block
// mapping (e = bid&7), scatter-A gather via tok_s, plain-store epilogue
// (slot0 -> out, slot1 -> part).
__global__ __launch_bounds__(512, 1) void expert_gemm(
    const bf16_t* __restrict__ xb, const bf16_t* __restrict__ wb,
    const float* __restrict__ eb, const int* __restrict__ cnt,
    const int* __restrict__ tok_list, const float* __restrict__ wgt_list,
    float* __restrict__ out, float* __restrict__ part) {
    int bid = blockIdx.x;
    int e = bid & 7;                          // XCD-resident expert
    int slot = bid >> 3;                      // 0..255 within expert
    int count = cnt[e * 16];
    int mt = (count + BM - 1) / BM;           // active m-tiles this expert
    if (slot >= mt * 8) return;
    int m0 = (slot >> 3) * BM;
    int n0 = (slot & 7) * BN;

    __shared__ alignas(16) unsigned char LDSB[131072];
    __shared__ int tok_s[BM];
    __shared__ float wgt_s[BM];

    int tid = threadIdx.x, wid = tid >> 6, L = tid & 63;
    int wr = wid >> 2, wc = wid & 3;          // 2 x 4 wave grid

    if (tid < BM) {
        int idx = m0 + tid;
        if (idx >= count) idx = count - 1;    // clamp; masked in epilogue
        tok_s[tid] = tok_list[e * T_TOK + idx];
        wgt_s[tid] = wgt_list[e * T_TOK + idx];
    }
    __syncthreads();

    // ---- staging geometry (r10 swizzle, conflict-free) ----
    int rA0 = wid * 16 + (L >> 2);            // call-0 row (0..127)
    int rA1 = rA0 + 128;                      // call-1 row
    int kcol = ((L & 3) ^ ((L >> 3) & 3)) * 8;  // pre-swizzled k-chunk (elems)
    const bf16_t* gA0 = xb + (size_t)(tok_s[rA0] >> 1) * D_DIM + kcol;
    const bf16_t* gA1 = xb + (size_t)(tok_s[rA1] >> 1) * D_DIM + kcol;
    const bf16_t* wbase = wb + (size_t)e * O_DIM * D_DIM;
    const bf16_t* gB0 = wbase + (size_t)(n0 + rA0) * D_DIM + kcol;
    const bf16_t* gB1 = wbase + (size_t)(n0 + rA1) * D_DIM + kcol;
    unsigned sW = wid * 1024;                 // wave-uniform LDS offset, call0

#define STAGE_A(db, hh, koff) do {                                          \
        unsigned bb = (db) * 65536u + (hh) * 16384u + sW;                   \
        gll16(gA0 + (koff), LDSB + bb);                                     \
        gll16(gA1 + (koff), LDSB + bb + 8192); } while (0)
#define STAGE_B(db, hh, koff) do {                                          \
        unsigned bb = (db) * 65536u + 32768u + (hh) * 16384u + sW;          \
        gll16(gB0 + (koff), LDSB + bb);                                     \
        gll16(gB1 + (koff), LDSB + bb + 8192); } while (0)

    // ---- read geometry (r10): slot = (L>>4) ^ ((L>>1)&3) ----
    unsigned xorp = ((unsigned)((L >> 4) ^ ((L >> 1) & 3))) * 16u;
    unsigned rowA = (unsigned)(wr * 128 + (L & 15)) * 64u;
    unsigned rowB = (unsigned)(wc * 64 + (L & 15)) * 64u;

#define LDA(base, MB)                                                       \
    _Pragma("unroll") for (int mm = 0; mm < 4; ++mm)                        \
        aq[mm] = *(const bf16x8*)(LDSB + (base) + rowA + (MB + mm) * 1024u + xorp);
#define LDB(base)                                                           \
    _Pragma("unroll") for (int nn = 0; nn < 4; ++nn)                        \
        bq[nn] = *(const bf16x8*)(LDSB + (base) + 32768u + rowB + nn * 1024u + xorp);
#define PH_MFMA(MB)                                                         \
    __builtin_amdgcn_s_setprio(1);                                          \
    _Pragma("unroll") for (int mm = 0; mm < 4; ++mm)                        \
        _Pragma("unroll") for (int nn = 0; nn < 4; ++nn)                    \
            acc[MB + mm][nn] = __builtin_amdgcn_mfma_f32_16x16x32_bf16(     \
                aq[mm], bq[nn], acc[MB + mm][nn], 0, 0, 0);                  \
    __builtin_amdgcn_s_setprio(0);
#define PHEND_LG  { asm volatile("s_waitcnt lgkmcnt(0)" ::: "memory");      \
                    __builtin_amdgcn_s_barrier();                           \
                    asm volatile("" ::: "memory"); }
#define PHEND_V8  { asm volatile("s_waitcnt vmcnt(8) lgkmcnt(0)" ::: "memory"); \
                    __builtin_amdgcn_s_barrier();                           \
                    asm volatile("" ::: "memory"); }
#define PHEND_V0  { asm volatile("s_waitcnt vmcnt(0) lgkmcnt(0)" ::: "memory"); \
                    __builtin_amdgcn_s_barrier();                           \
                    asm volatile("" ::: "memory"); }

    fx4 acc[8][4];
#pragma unroll
    for (int m = 0; m < 8; ++m)
#pragma unroll
        for (int n = 0; n < 4; ++n) acc[m][n] = (fx4)0.f;

    const int NT = D_DIM / BK;                // 32
    // prologue: tile0 all 4 halves -> dbuf0, tile1 kh0 -> dbuf1.
    STAGE_A(0, 0, 0);   STAGE_B(0, 0, 0);
    STAGE_A(0, 1, 32);  STAGE_B(0, 1, 32);
    STAGE_A(1, 0, 64);  STAGE_B(1, 0, 64);
    PHEND_V8;

    for (int t = 0; t < NT; ++t) {
        const int d = t & 1;
        const unsigned CA = (unsigned)d * 65536u;
        bf16x8 aq[4], bq[4];
        // ---- ph1: kh0, m0-3 (+B kh0) ----
        LDA(CA, 0); LDB(CA);
        if (t + 1 < NT) STAGE_A(d ^ 1, 1, (t + 1) * 64 + 32);
        PHEND_LG;
        PH_MFMA(0);
        // ---- ph2: kh0, m4-7 (B reused in regs) ----
        LDA(CA, 4);
        if (t + 1 < NT) { STAGE_B(d ^ 1, 1, (t + 1) * 64 + 32); PHEND_V8; }
        else            { PHEND_V0; }
        PH_MFMA(4);
        // ---- ph3: kh1, m0-3 (+B kh1) ----
        LDA(CA + 16384u, 0); LDB(CA + 16384u);
        if (t + 2 < NT) STAGE_A(d, 0, (t + 2) * 64);
        PHEND_LG;
        PH_MFMA(0);
        // ---- ph4: kh1, m4-7 ----
        LDA(CA + 16384u, 4);
        if (t + 2 < NT) { STAGE_B(d, 0, (t + 2) * 64); PHEND_V8; }
        else            { PHEND_V0; }
        PH_MFMA(4);
    }
#undef STAGE_A
#undef STAGE_B
#undef LDA
#undef LDB
#undef PH_MFMA
#undef PHEND_LG
#undef PHEND_V8
#undef PHEND_V0

    // epilogue: C/D layout col=L&15, row=(L>>4)*4+j. Plain scatter stores.
    const float* ebias = eb + (size_t)e * O_DIM;
    int rr = L & 15, kq = L >> 4;
#pragma unroll
    for (int n = 0; n < 4; ++n) {
        int gcol = n0 + wc * 64 + n * 16 + rr;
        float bias = ebias[gcol];
#pragma unroll
        for (int m = 0; m < 8; ++m) {
            int rbase = wr * 128 + m * 16 + kq * 4;
#pragma unroll
            for (int j = 0; j < 4; ++j) {
                int r = rbase + j;
                if (m0 + r < count) {
                    int entry = tok_s[r];
                    float v = wgt_s[r] * (acc[m][n][j] + bias);
                    float* dst = (entry & 1) ? part : out;
                    dst[(size_t)(entry >> 1) * O_DIM + gcol] = v;
                }
            }
        }
    }
}

// ---------------------------------------------------------------- combine
__global__ __launch_bounds__(256) void combine_kernel(
    float* __restrict__ out, const float* __restrict__ part, long n4) {
    long i = (long)blockIdx.x * blockDim.x + threadIdx.x;
    long stride = (long)gridDim.x * blockDim.x;
    float4* o4 = (float4*)out;
    const float4* p4 = (const float4*)part;
    for (; i < n4; i += stride) {
        float4 a = o4[i], b = p4[i];
        a.x += b.x; a.y += b.y; a.z += b.z; a.w += b.w;
        o4[i] = a;
    }
}

// ---------------------------------------------------------------- launch
extern "C" void kernel_launch(void* const* d_in, const int* in_sizes, int n_in,
                              void* d_out, int out_size, void* d_ws, size_t ws_size,
                              hipStream_t stream) {
    const float* x        = (const float*)d_in[0];
    const float* gate_w   = (const float*)d_in[1];
    const float* expert_w = (const float*)d_in[2];
    const float* expert_b = (const float*)d_in[3];
    float* out = (float*)d_out;

    char* ws = (char*)d_ws;
    size_t off = 0;
    bf16_t* wb = (bf16_t*)(ws + off);      off += (size_t)E_NUM * O_DIM * D_DIM * 2;
    bf16_t* xb = (bf16_t*)(ws + off);      off += (size_t)T_TOK * D_DIM * 2;
    float*  part = (float*)(ws + off);     off += (size_t)T_TOK * O_DIM * 4;
    int*    tok_list = (int*)(ws + off);   off += (size_t)E_NUM * T_TOK * 4;
    float*  wgt_list = (float*)(ws + off); off += (size_t)E_NUM * T_TOK * 4;
    int*    cnt = (int*)(ws + off);        off += 512;   // 8 counters, 64B apart

    convert_w_kernel<<<4096, 256, 0, stream>>>(expert_w, wb, cnt);
    gate_kernel<<<T_TOK / 4, 256, 0, stream>>>(
        x, gate_w, xb, cnt, tok_list, wgt_list);
    expert_gemm<<<2048, 512, 0, stream>>>(
        xb, wb, expert_b, cnt, tok_list, wgt_list, out, part);
    combine_kernel<<<2048, 256, 0, stream>>>(
        out, part, (long)T_TOK * O_DIM / 4);
}